// Round 9
// baseline (344.056 us; speedup 1.0000x reference)
//
#include <hip/hip_runtime.h>
#include <hip/hip_fp16.h>

#define B_ 16
#define N_ 785
#define C_ 768
#define H_ 12
#define HD_ 64
#define P_ 48
#define M_ (B_*N_)      // 12560
#define POSW 832        // padded row stride (halves) for pos bias (13*64)
#define SLOG2E 0.1803368801111244f   // (hd^-0.5) * log2(e)

// ws layout (fp16 element offsets)
#define OFF_Q   0                    //  9,646,080
#define OFF_K   9646080              //  9,646,080
#define OFF_V   19292160             //  9,646,080 (row-major, same as K)
#define OFF_POS 29515776             //  7,837,440 (12*785*832)
#define OFF_XF  37353216             //  9,732,096 (12672*768) — x-f16, later attn-out
#define OFF_AO  OFF_XF               //  alias: x dead after qkv_gemm
#define OFF_WQ  47085312             //  1,769,472 (2304*768)
#define OFF_WP  48854784             //    589,824 (768*768)  end: 49,444,608 halves

struct __align__(16) Half8 { __half h[8]; };
typedef _Float16 half8_t __attribute__((ext_vector_type(8)));
typedef _Float16 half4_t __attribute__((ext_vector_type(4)));
typedef float f32x4 __attribute__((ext_vector_type(4)));

__device__ __forceinline__ void gl16(const void* g, void* l) {
    __builtin_amdgcn_global_load_lds(
        (const __attribute__((address_space(1))) void*)g,
        (__attribute__((address_space(3))) void*)l, 16, 0, 0);
}

// bijective XCD-chunked swizzle (m204)
__device__ __forceinline__ int xcd_swz(int o, int nwg) {
    const int q = nwg >> 3, r = nwg & 7;
    const int xcd = o & 7, idx = o >> 3;
    const int base = xcd < r ? xcd * (q + 1) : r * (q + 1) + (xcd - r) * q;
    return base + idx;
}

// ---------------------------------------------------------------------------
// K0: fp32 -> fp16 convert of x, qkv_w, proj_w
// ---------------------------------------------------------------------------
#define NX4 2411520
#define NQ4 442368
#define NP4 147456
#define NTOT4 (NX4+NQ4+NP4)   // 3,001,344 = 11724 * 256

__global__ __launch_bounds__(256) void convert_f16(
    const float* __restrict__ x, const float* __restrict__ wq,
    const float* __restrict__ wp, _Float16* __restrict__ xo,
    _Float16* __restrict__ wqo, _Float16* __restrict__ wpo)
{
    int i = blockIdx.x * 256 + threadIdx.x;
    const float4* s; _Float16* d; int o;
    if (i < NX4)            { s = (const float4*)x;  d = xo;  o = i; }
    else if (i < NX4 + NQ4) { s = (const float4*)wq; d = wqo; o = i - NX4; }
    else                    { s = (const float4*)wp; d = wpo; o = i - NX4 - NQ4; }
    float4 v = s[o];
    half4_t h = { (_Float16)v.x, (_Float16)v.y, (_Float16)v.z, (_Float16)v.w };
    *(half4_t*)&d[o * 4] = h;
}

// ---------------------------------------------------------------------------
// K1: qkv MFMA GEMM, double-buffered LDS + XCD swizzle. q/k/v all row-major.
// ---------------------------------------------------------------------------
#define QKV_NWG (18 * 99)

__global__ __launch_bounds__(256) void qkv_gemm_mfma(
    const _Float16* __restrict__ A, const _Float16* __restrict__ Bw,
    __half* __restrict__ qh, __half* __restrict__ kh, __half* __restrict__ vh)
{
    __shared__ _Float16 Asl[2][128 * 32];
    __shared__ _Float16 Bsl[2][128 * 32];

    const int t  = threadIdx.x;
    const int w  = t >> 6;
    const int l  = t & 63;
    const int lr = l & 15;
    const int lg = l >> 4;
    const int wm = (w >> 1) * 64;
    const int wn = (w & 1) * 64;

    const int g  = xcd_swz(blockIdx.x, QKV_NWG);
    const int nt = g % 18;
    const int n0 = nt * 128;
    const int m0 = (g / 18) * 128;

    const int f1 = t + 256;
    const int ar0 = t >> 2,  ac0 = (t & 3) * 8;
    const int ar1 = f1 >> 2, ac1 = (f1 & 3) * 8;
    const _Float16* Ag0 = A  + (size_t)(m0 + ar0) * 768 + ac0;
    const _Float16* Ag1 = A  + (size_t)(m0 + ar1) * 768 + ac1;
    const _Float16* Bg0 = Bw + (size_t)(n0 + ar0) * 768 + ac0;
    const _Float16* Bg1 = Bw + (size_t)(n0 + ar1) * 768 + ac1;

    f32x4 acc[4][4];
    #pragma unroll
    for (int i = 0; i < 4; ++i)
        #pragma unroll
        for (int j = 0; j < 4; ++j) acc[i][j] = (f32x4){0.f, 0.f, 0.f, 0.f};

    gl16(Ag0, &Asl[0][t * 8]); gl16(Ag1, &Asl[0][f1 * 8]);
    gl16(Bg0, &Bsl[0][t * 8]); gl16(Bg1, &Bsl[0][f1 * 8]);
    __syncthreads();

    #pragma unroll 2
    for (int it = 0; it < 24; ++it) {
        const int cur = it & 1;
        if (it < 23) {
            const int kn = (it + 1) * 32;
            gl16(Ag0 + kn, &Asl[cur ^ 1][t * 8]); gl16(Ag1 + kn, &Asl[cur ^ 1][f1 * 8]);
            gl16(Bg0 + kn, &Bsl[cur ^ 1][t * 8]); gl16(Bg1 + kn, &Bsl[cur ^ 1][f1 * 8]);
        }
        half8_t af[4], bf[4];
        #pragma unroll
        for (int i = 0; i < 4; ++i)
            af[i] = *(const half8_t*)&Asl[cur][(wm + i * 16 + lr) * 32 + lg * 8];
        #pragma unroll
        for (int j = 0; j < 4; ++j)
            bf[j] = *(const half8_t*)&Bsl[cur][(wn + j * 16 + lr) * 32 + lg * 8];
        __builtin_amdgcn_s_setprio(1);
        #pragma unroll
        for (int i = 0; i < 4; ++i)
            #pragma unroll
            for (int j = 0; j < 4; ++j)
                acc[i][j] = __builtin_amdgcn_mfma_f32_16x16x32_f16(af[i], bf[j], acc[i][j], 0, 0, 0);
        __builtin_amdgcn_s_setprio(0);
        __syncthreads();
    }

    const int tsel  = nt / 6;          // 0=q 1=k 2=v
    const int nbase = n0 - tsel * 768;
    #pragma unroll
    for (int i = 0; i < 4; ++i) {
        #pragma unroll
        for (int r = 0; r < 4; ++r) {
            const int m = m0 + wm + i * 16 + lg * 4 + r;
            if (m >= M_) continue;
            const int bb = m / N_, nn = m - bb * N_;
            #pragma unroll
            for (int j = 0; j < 4; ++j) {
                const int nsec = nbase + wn + j * 16 + lr;
                const int hh = nsec >> 6, dd = nsec & 63;
                const float v = acc[i][j][r];
                const size_t dst = ((size_t)(bb * H_ + hh) * N_ + nn) * HD_ + dd;
                if (tsel == 0)      qh[dst] = __float2half(v * SLOG2E);
                else if (tsel == 1) kh[dst] = __float2half(v);
                else                vh[dst] = __float2half(v);
            }
        }
    }
}

// ---------------------------------------------------------------------------
// K2: pos bias (scaled by SCALE*log2e): posh[h][n][m]
// ---------------------------------------------------------------------------
__global__ __launch_bounds__(256) void pos_kernel(
    const float* __restrict__ pe, const float* __restrict__ pw,
    __half* __restrict__ posh)
{
    __shared__ float W[H_][P_];
    const int t = threadIdx.x;
    for (int i = t; i < H_ * P_; i += 256) W[i / P_][i % P_] = pw[i];
    __syncthreads();
    int nm = blockIdx.x * 256 + t;
    if (nm >= N_ * N_) return;
    float e[48];
    const float4* src = (const float4*)(pe + (size_t)nm * 48);
    #pragma unroll
    for (int i = 0; i < 12; ++i) {
        float4 v = src[i];
        e[4*i] = v.x; e[4*i+1] = v.y; e[4*i+2] = v.z; e[4*i+3] = v.w;
    }
    int n = nm / N_, m = nm - n * N_;
    #pragma unroll
    for (int hh = 0; hh < H_; ++hh) {
        float s = 0.f;
        #pragma unroll
        for (int p = 0; p < 48; ++p) s = fmaf(e[p], W[hh][p], s);
        posh[((size_t)hh * N_ + n) * POSW + m] = __float2half(s * SLOG2E);
    }
}

// ---------------------------------------------------------------------------
// K3: split-KEY MFMA flash attention. Wave w owns keys w*16..w*16+15 of each
//     64-key chunk for ALL 64 q-rows. LDS reads = chunk size (no 4x wave
//     amplification). P feeds 16x16x16 PV directly; V row-major. 4-wave
//     (m,l,O) merge via LDS at end.
// ---------------------------------------------------------------------------
#define NQT 13
#define ATT_NWG (192 * NQT)   // 2496, divisible by 8

__global__ __launch_bounds__(256) void attn_mfma(
    const _Float16* __restrict__ qh, const _Float16* __restrict__ kh,
    const _Float16* __restrict__ vh, const _Float16* __restrict__ posh,
    _Float16* __restrict__ aoh)
{
    __shared__ __align__(16) char smem[28672];
    _Float16 (*Kl)[72] = (_Float16 (*)[72])(smem);           //  0    .. 9215
    _Float16 (*Vl)[72] = (_Float16 (*)[72])(smem + 9216);    //  9216 .. 18431
    _Float16 (*Bl)[72] = (_Float16 (*)[72])(smem + 18432);   // 18432 .. 27647
    float    (*Ol)[68] = (float (*)[68])(smem);              // merge: 0..17407
    float*    Ml       = (float*)(smem + 17408);             // 4*64 f32
    float*    Ll       = (float*)(smem + 18432);             // 4*64 f32

    const int t  = threadIdx.x;
    const int w  = t >> 6;                   // wave = key-quarter owner
    const int l  = t & 63;
    const int lr = l & 15;
    const int lg = l >> 4;

    const int g2   = xcd_swz(blockIdx.x, ATT_NWG);
    const int qt   = g2 % NQT;
    const int rest = g2 / NQT;
    const int b    = rest & 15;
    const int h    = rest >> 4;
    const int bh   = b * H_ + h;
    const int n0   = qt * 64;

    // Q fragments for ALL 64 q-rows (B-operand: lane lr = q within group)
    half8_t Qf0[4], Qf1[4];
    #pragma unroll
    for (int qg = 0; qg < 4; ++qg) {
        const int qr = min(n0 + qg * 16 + lr, N_ - 1);
        const _Float16* qb = qh + ((size_t)bh * N_ + qr) * HD_;
        Qf0[qg] = *(const half8_t*)(qb + lg * 8);
        Qf1[qg] = *(const half8_t*)(qb + 32 + lg * 8);
    }

    f32x4 O[4][4];
    #pragma unroll
    for (int qg = 0; qg < 4; ++qg)
        #pragma unroll
        for (int ds = 0; ds < 4; ++ds) O[qg][ds] = (f32x4){0.f, 0.f, 0.f, 0.f};
    float m_r[4] = {-1e30f, -1e30f, -1e30f, -1e30f};   // per (wave, q=qg*16+lr)
    float lp[4]  = {0.f, 0.f, 0.f, 0.f};               // per-lane partial denom

    const int srow = t >> 2;
    const int scol = (t & 3) * 16;
    const _Float16* kRow = kh + ((size_t)bh * N_) * HD_ + scol;
    const _Float16* vRow = vh + ((size_t)bh * N_) * HD_ + scol;
    const _Float16* bRow = posh + ((size_t)h * N_ + min(n0 + srow, N_ - 1)) * POSW + scol;

    half8_t rk0, rk1, rv0, rv1, rb0, rb1;
    {
        const int gm = min(srow, N_ - 1);
        const half8_t* ks = (const half8_t*)(kRow + (size_t)gm * HD_);
        rk0 = ks[0]; rk1 = ks[1];
        const half8_t* vs = (const half8_t*)(vRow + (size_t)gm * HD_);
        rv0 = vs[0]; rv1 = vs[1];
        const half8_t* bs = (const half8_t*)bRow;
        rb0 = bs[0]; rb1 = bs[1];
    }

    for (int c = 0; c < 13; ++c) {
        *(half8_t*)&Kl[srow][scol]     = rk0;
        *(half8_t*)&Kl[srow][scol + 8] = rk1;
        *(half8_t*)&Vl[srow][scol]     = rv0;
        *(half8_t*)&Vl[srow][scol + 8] = rv1;
        *(half8_t*)&Bl[srow][scol]     = rb0;
        *(half8_t*)&Bl[srow][scol + 8] = rb1;
        __syncthreads();

        if (c < 12) {
            const int m0n = (c + 1) * 64;
            const int gm  = min(m0n + srow, N_ - 1);
            const half8_t* ks = (const half8_t*)(kRow + (size_t)gm * HD_);
            rk0 = ks[0]; rk1 = ks[1];
            const half8_t* vs = (const half8_t*)(vRow + (size_t)gm * HD_);
            rv0 = vs[0]; rv1 = vs[1];
            const half8_t* bs = (const half8_t*)(bRow + m0n);
            rb0 = bs[0]; rb1 = bs[1];
        }

        // ---- QK^T for this wave's 16 keys: s[qg][r] = P[key=w*16+lg*4+r][q=qg*16+lr]
        const half8_t k0 = *(const half8_t*)&Kl[w * 16 + lr][lg * 8];
        const half8_t k1 = *(const half8_t*)&Kl[w * 16 + lr][32 + lg * 8];
        f32x4 s[4];
        __builtin_amdgcn_s_setprio(1);
        #pragma unroll
        for (int qg = 0; qg < 4; ++qg) {
            half4_t b4 = *(const half4_t*)&Bl[qg * 16 + lr][w * 16 + lg * 4];
            f32x4 acc = { (float)b4[0], (float)b4[1], (float)b4[2], (float)b4[3] };
            acc = __builtin_amdgcn_mfma_f32_16x16x32_f16(k0, Qf0[qg], acc, 0, 0, 0);
            acc = __builtin_amdgcn_mfma_f32_16x16x32_f16(k1, Qf1[qg], acc, 0, 0, 0);
            s[qg] = acc;
        }
        __builtin_amdgcn_s_setprio(0);

        // ---- key-validity mask (last chunk: only in-chunk keys < 17 valid)
        if (c == 12) {
            #pragma unroll
            for (int qg = 0; qg < 4; ++qg)
                #pragma unroll
                for (int r = 0; r < 4; ++r)
                    if (w * 16 + lg * 4 + r >= 17) s[qg][r] = -1e30f;
        }

        // ---- defer-max online softmax: no cross-lane ops on the common path
        float mq[4];
        #pragma unroll
        for (int qg = 0; qg < 4; ++qg)
            mq[qg] = fmaxf(fmaxf(s[qg][0], s[qg][1]), fmaxf(s[qg][2], s[qg][3]));
        const bool trig = (mq[0] > m_r[0] + 8.f) || (mq[1] > m_r[1] + 8.f) ||
                          (mq[2] > m_r[2] + 8.f) || (mq[3] > m_r[3] + 8.f);
        if (__any(trig)) {
            #pragma unroll
            for (int qg = 0; qg < 4; ++qg) {
                float v = fmaxf(mq[qg], __shfl_xor(mq[qg], 16));
                v = fmaxf(v, __shfl_xor(v, 32));
                const float mn = fmaxf(m_r[qg], v);
                const float al = exp2f(m_r[qg] - mn);
                m_r[qg] = mn;
                lp[qg] *= al;
                f32x4 av;
                #pragma unroll
                for (int r = 0; r < 4; ++r) av[r] = __shfl(al, lg * 4 + r);
                #pragma unroll
                for (int ds = 0; ds < 4; ++ds) O[qg][ds] *= av;
            }
        }

        // ---- P = exp2(s - m); per-lane partial denom; direct A-frag pack
        half4_t pf[4];
        #pragma unroll
        for (int qg = 0; qg < 4; ++qg) {
            float p0 = exp2f(s[qg][0] - m_r[qg]);
            float p1 = exp2f(s[qg][1] - m_r[qg]);
            float p2 = exp2f(s[qg][2] - m_r[qg]);
            float p3 = exp2f(s[qg][3] - m_r[qg]);
            lp[qg] += (p0 + p1) + (p2 + p3);
            pf[qg] = (half4_t){ (_Float16)p0, (_Float16)p1, (_Float16)p2, (_Float16)p3 };
        }

        // ---- PV: B[k=key][col=d] from row-major V; 16 x mfma 16x16x16
        __builtin_amdgcn_s_setprio(1);
        #pragma unroll
        for (int ds = 0; ds < 4; ++ds) {
            half4_t vb;
            #pragma unroll
            for (int i = 0; i < 4; ++i)
                vb[i] = Vl[w * 16 + lg * 4 + i][ds * 16 + lr];
            #pragma unroll
            for (int qg = 0; qg < 4; ++qg)
                O[qg][ds] = __builtin_amdgcn_mfma_f32_16x16x16f16(pf[qg], vb, O[qg][ds], 0, 0, 0);
        }
        __builtin_amdgcn_s_setprio(0);
        __syncthreads();
    }

    // ---- 4-wave merge: m exchange -> rescale -> l reduce -> O accumulate
    if (lg == 0) {
        #pragma unroll
        for (int qg = 0; qg < 4; ++qg) Ml[w * 64 + qg * 16 + lr] = m_r[qg];
    }
    __syncthreads();
    f32x4 av[4];
    #pragma unroll
    for (int qg = 0; qg < 4; ++qg) {
        const int q = qg * 16 + lr;
        const float mt = fmaxf(fmaxf(Ml[q], Ml[64 + q]), fmaxf(Ml[128 + q], Ml[192 + q]));
        const float aw = exp2f(m_r[qg] - mt);
        float lw = lp[qg] * aw;
        lw += __shfl_xor(lw, 16);
        lw += __shfl_xor(lw, 32);
        if (lg == 0) Ll[w * 64 + q] = lw;
        #pragma unroll
        for (int r = 0; r < 4; ++r) av[qg][r] = __shfl(aw, lg * 4 + r);
    }
    #pragma unroll
    for (int wp = 0; wp < 4; ++wp) {
        __syncthreads();
        if (w == wp) {
            #pragma unroll
            for (int qg = 0; qg < 4; ++qg)
                #pragma unroll
                for (int ds = 0; ds < 4; ++ds)
                    #pragma unroll
                    for (int r = 0; r < 4; ++r) {
                        const float val = O[qg][ds][r] * av[qg][r];
                        float* slot = &Ol[qg * 16 + lg * 4 + r][ds * 16 + lr];
                        if (wp == 0) *slot = val;
                        else         *slot += val;
                    }
        }
    }
    __syncthreads();

    // ---- normalize + store: thread t -> q = t>>2, d-group = (t&3)*16
    {
        const int q  = t >> 2;
        const int dg = (t & 3) * 16;
        const int n  = n0 + q;
        if (n < N_) {
            const float lt = Ll[q] + Ll[64 + q] + Ll[128 + q] + Ll[192 + q];
            const float inv = 1.f / lt;
            const float* src = &Ol[q][dg];
            half8_t o0, o1;
            #pragma unroll
            for (int e = 0; e < 8; ++e) {
                o0[e] = (_Float16)(src[e] * inv);
                o1[e] = (_Float16)(src[8 + e] * inv);
            }
            _Float16* dst = aoh + ((size_t)((bh / H_) * N_ + n)) * C_ + h * HD_ + dg;
            *(half8_t*)dst = o0;
            *(half8_t*)(dst + 8) = o1;
        }
    }
}

// ---------------------------------------------------------------------------
// K4: proj MFMA GEMM, double-buffered + XCD swizzle: out = AO @ Wp^T + bias
// ---------------------------------------------------------------------------
#define PROJ_NWG (6 * 99)

__global__ __launch_bounds__(256) void proj_gemm_mfma(
    const _Float16* __restrict__ A, const _Float16* __restrict__ Bw,
    const float* __restrict__ bias, float* __restrict__ out)
{
    __shared__ _Float16 Asl[2][128 * 32];
    __shared__ _Float16 Bsl[2][128 * 32];

    const int t  = threadIdx.x;
    const int w  = t >> 6;
    const int l  = t & 63;
    const int lr = l & 15;
    const int lg = l >> 4;
    const int wm = (w >> 1) * 64;
    const int wn = (w & 1) * 64;

    const int g  = xcd_swz(blockIdx.x, PROJ_NWG);
    const int n0 = (g % 6) * 128;
    const int m0 = (g / 6) * 128;

    const int f1 = t + 256;
    const int ar0 = t >> 2,  ac0 = (t & 3) * 8;
    const int ar1 = f1 >> 2, ac1 = (f1 & 3) * 8;
    const _Float16* Ag0 = A  + (size_t)(m0 + ar0) * 768 + ac0;
    const _Float16* Ag1 = A  + (size_t)(m0 + ar1) * 768 + ac1;
    const _Float16* Bg0 = Bw + (size_t)(n0 + ar0) * 768 + ac0;
    const _Float16* Bg1 = Bw + (size_t)(n0 + ar1) * 768 + ac1;

    f32x4 acc[4][4];
    #pragma unroll
    for (int i = 0; i < 4; ++i)
        #pragma unroll
        for (int j = 0; j < 4; ++j) acc[i][j] = (f32x4){0.f, 0.f, 0.f, 0.f};

    gl16(Ag0, &Asl[0][t * 8]); gl16(Ag1, &Asl[0][f1 * 8]);
    gl16(Bg0, &Bsl[0][t * 8]); gl16(Bg1, &Bsl[0][f1 * 8]);
    __syncthreads();

    #pragma unroll 2
    for (int it = 0; it < 24; ++it) {
        const int cur = it & 1;
        if (it < 23) {
            const int kn = (it + 1) * 32;
            gl16(Ag0 + kn, &Asl[cur ^ 1][t * 8]); gl16(Ag1 + kn, &Asl[cur ^ 1][f1 * 8]);
            gl16(Bg0 + kn, &Bsl[cur ^ 1][t * 8]); gl16(Bg1 + kn, &Bsl[cur ^ 1][f1 * 8]);
        }
        half8_t af[4], bf[4];
        #pragma unroll
        for (int i = 0; i < 4; ++i)
            af[i] = *(const half8_t*)&Asl[cur][(wm + i * 16 + lr) * 32 + lg * 8];
        #pragma unroll
        for (int j = 0; j < 4; ++j)
            bf[j] = *(const half8_t*)&Bsl[cur][(wn + j * 16 + lr) * 32 + lg * 8];
        __builtin_amdgcn_s_setprio(1);
        #pragma unroll
        for (int i = 0; i < 4; ++i)
            #pragma unroll
            for (int j = 0; j < 4; ++j)
                acc[i][j] = __builtin_amdgcn_mfma_f32_16x16x32_f16(af[i], bf[j], acc[i][j], 0, 0, 0);
        __builtin_amdgcn_s_setprio(0);
        __syncthreads();
    }

    float bj[4];
    #pragma unroll
    for (int j = 0; j < 4; ++j) bj[j] = bias[n0 + wn + j * 16 + lr];
    #pragma unroll
    for (int i = 0; i < 4; ++i) {
        #pragma unroll
        for (int r = 0; r < 4; ++r) {
            const int m = m0 + wm + i * 16 + lg * 4 + r;
            if (m >= M_) continue;
            #pragma unroll
            for (int j = 0; j < 4; ++j) {
                const int n = n0 + wn + j * 16 + lr;
                out[(size_t)m * 768 + n] = acc[i][j][r] + bj[j];
            }
        }
    }
}

// ---------------------------------------------------------------------------
extern "C" void kernel_launch(void* const* d_in, const int* in_sizes, int n_in,
                              void* d_out, int out_size, void* d_ws, size_t ws_size,
                              hipStream_t stream)
{
    const float* x     = (const float*)d_in[0];
    const float* qkv_w = (const float*)d_in[1];
    const float* pe    = (const float*)d_in[2];
    const float* pw    = (const float*)d_in[3];
    const float* pjw   = (const float*)d_in[4];
    const float* pjb   = (const float*)d_in[5];
    float* out = (float*)d_out;

    _Float16* wsh  = (_Float16*)d_ws;
    _Float16* qh   = wsh + OFF_Q;
    _Float16* kh   = wsh + OFF_K;
    _Float16* vh   = wsh + OFF_V;
    _Float16* posh = wsh + OFF_POS;
    _Float16* xf   = wsh + OFF_XF;
    _Float16* aoh  = wsh + OFF_AO;       // aliases xf (x dead after qkv_gemm)
    _Float16* wqf  = wsh + OFF_WQ;
    _Float16* wpf  = wsh + OFF_WP;

    convert_f16<<<dim3(NTOT4 / 256), 256, 0, stream>>>(x, qkv_w, pjw, xf, wqf, wpf);
    qkv_gemm_mfma<<<dim3(QKV_NWG), 256, 0, stream>>>(
        xf, wqf, (__half*)qh, (__half*)kh, (__half*)vh);
    pos_kernel<<<dim3((N_ * N_ + 255) / 256), 256, 0, stream>>>(pe, pw, (__half*)posh);
    attn_mfma<<<dim3(ATT_NWG), 256, 0, stream>>>(qh, kh, vh, posh, aoh);
    proj_gemm_mfma<<<dim3(PROJ_NWG), 256, 0, stream>>>(aoh, wpf, pjb, out);
}

// Round 10
// 260.845 us; speedup vs baseline: 1.3190x; 1.3190x over previous
//
#include <hip/hip_runtime.h>
#include <hip/hip_fp16.h>

#define B_ 16
#define N_ 785
#define C_ 768
#define H_ 12
#define HD_ 64
#define P_ 48
#define M_ (B_*N_)      // 12560
#define POSW 832        // padded row stride (halves) for pos bias (13*64)
#define VTW  832        // padded row stride (halves) for V^T
#define SLOG2E 0.1803368801111244f   // (hd^-0.5) * log2(e)

// ws layout (fp16 element offsets)
#define OFF_Q   0                    //  9,646,080
#define OFF_K   9646080              //  9,646,080
#define OFF_VT  19292160             // 10,223,616 (16*12*64*832)
#define OFF_POS 29515776             //  7,837,440 (12*785*832)
#define OFF_XF  37353216             //  9,732,096 (12672*768) — x-f16, later attn-out
#define OFF_AO  OFF_XF               //  alias: x dead after qkv_gemm
#define OFF_WQ  47085312             //  1,769,472 (2304*768)
#define OFF_WP  48854784             //    589,824 (768*768)  end: 49,444,608 halves

struct __align__(16) Half8 { __half h[8]; };
typedef _Float16 half8_t __attribute__((ext_vector_type(8)));
typedef _Float16 half4_t __attribute__((ext_vector_type(4)));
typedef float f32x4 __attribute__((ext_vector_type(4)));

__device__ __forceinline__ void gl16(const void* g, void* l) {
    __builtin_amdgcn_global_load_lds(
        (const __attribute__((address_space(1))) void*)g,
        (__attribute__((address_space(3))) void*)l, 16, 0, 0);
}

// bijective XCD-chunked swizzle (m204)
__device__ __forceinline__ int xcd_swz(int o, int nwg) {
    const int q = nwg >> 3, r = nwg & 7;
    const int xcd = o & 7, idx = o >> 3;
    const int base = xcd < r ? xcd * (q + 1) : r * (q + 1) + (xcd - r) * q;
    return base + idx;
}

// ---------------------------------------------------------------------------
// K0: fp32 -> fp16 convert of x, qkv_w, proj_w
// ---------------------------------------------------------------------------
#define NX4 2411520
#define NQ4 442368
#define NP4 147456
#define NTOT4 (NX4+NQ4+NP4)   // 3,001,344 = 11724 * 256

__global__ __launch_bounds__(256) void convert_f16(
    const float* __restrict__ x, const float* __restrict__ wq,
    const float* __restrict__ wp, _Float16* __restrict__ xo,
    _Float16* __restrict__ wqo, _Float16* __restrict__ wpo)
{
    int i = blockIdx.x * 256 + threadIdx.x;
    const float4* s; _Float16* d; int o;
    if (i < NX4)            { s = (const float4*)x;  d = xo;  o = i; }
    else if (i < NX4 + NQ4) { s = (const float4*)wq; d = wqo; o = i - NX4; }
    else                    { s = (const float4*)wp; d = wpo; o = i - NX4 - NQ4; }
    float4 v = s[o];
    half4_t h = { (_Float16)v.x, (_Float16)v.y, (_Float16)v.z, (_Float16)v.w };
    *(half4_t*)&d[o * 4] = h;
}

// ---------------------------------------------------------------------------
// K1: qkv MFMA GEMM, double-buffered LDS + XCD swizzle
// ---------------------------------------------------------------------------
#define QKV_NWG (18 * 99)

__global__ __launch_bounds__(256) void qkv_gemm_mfma(
    const _Float16* __restrict__ A, const _Float16* __restrict__ Bw,
    __half* __restrict__ qh, __half* __restrict__ kh, __half* __restrict__ vth)
{
    __shared__ _Float16 Asl[2][128 * 32];
    __shared__ _Float16 Bsl[2][128 * 32];

    const int t  = threadIdx.x;
    const int w  = t >> 6;
    const int l  = t & 63;
    const int lr = l & 15;
    const int lg = l >> 4;
    const int wm = (w >> 1) * 64;
    const int wn = (w & 1) * 64;

    const int g  = xcd_swz(blockIdx.x, QKV_NWG);
    const int nt = g % 18;
    const int n0 = nt * 128;
    const int m0 = (g / 18) * 128;

    const int f1 = t + 256;
    const int ar0 = t >> 2,  ac0 = (t & 3) * 8;
    const int ar1 = f1 >> 2, ac1 = (f1 & 3) * 8;
    const _Float16* Ag0 = A  + (size_t)(m0 + ar0) * 768 + ac0;
    const _Float16* Ag1 = A  + (size_t)(m0 + ar1) * 768 + ac1;
    const _Float16* Bg0 = Bw + (size_t)(n0 + ar0) * 768 + ac0;
    const _Float16* Bg1 = Bw + (size_t)(n0 + ar1) * 768 + ac1;

    f32x4 acc[4][4];
    #pragma unroll
    for (int i = 0; i < 4; ++i)
        #pragma unroll
        for (int j = 0; j < 4; ++j) acc[i][j] = (f32x4){0.f, 0.f, 0.f, 0.f};

    gl16(Ag0, &Asl[0][t * 8]); gl16(Ag1, &Asl[0][f1 * 8]);
    gl16(Bg0, &Bsl[0][t * 8]); gl16(Bg1, &Bsl[0][f1 * 8]);
    __syncthreads();

    #pragma unroll 2
    for (int it = 0; it < 24; ++it) {
        const int cur = it & 1;
        if (it < 23) {
            const int kn = (it + 1) * 32;
            gl16(Ag0 + kn, &Asl[cur ^ 1][t * 8]); gl16(Ag1 + kn, &Asl[cur ^ 1][f1 * 8]);
            gl16(Bg0 + kn, &Bsl[cur ^ 1][t * 8]); gl16(Bg1 + kn, &Bsl[cur ^ 1][f1 * 8]);
        }
        half8_t af[4], bf[4];
        #pragma unroll
        for (int i = 0; i < 4; ++i)
            af[i] = *(const half8_t*)&Asl[cur][(wm + i * 16 + lr) * 32 + lg * 8];
        #pragma unroll
        for (int j = 0; j < 4; ++j)
            bf[j] = *(const half8_t*)&Bsl[cur][(wn + j * 16 + lr) * 32 + lg * 8];
        __builtin_amdgcn_s_setprio(1);
        #pragma unroll
        for (int i = 0; i < 4; ++i)
            #pragma unroll
            for (int j = 0; j < 4; ++j)
                acc[i][j] = __builtin_amdgcn_mfma_f32_16x16x32_f16(af[i], bf[j], acc[i][j], 0, 0, 0);
        __builtin_amdgcn_s_setprio(0);
        __syncthreads();
    }

    const int tsel  = nt / 6;          // 0=q 1=k 2=v
    const int nbase = n0 - tsel * 768;
    #pragma unroll
    for (int i = 0; i < 4; ++i) {
        #pragma unroll
        for (int r = 0; r < 4; ++r) {
            const int m = m0 + wm + i * 16 + lg * 4 + r;
            if (m >= M_) continue;
            const int bb = m / N_, nn = m - bb * N_;
            #pragma unroll
            for (int j = 0; j < 4; ++j) {
                const int nsec = nbase + wn + j * 16 + lr;
                const int hh = nsec >> 6, dd = nsec & 63;
                const float v = acc[i][j][r];
                if (tsel == 0)
                    qh[((size_t)(bb * H_ + hh) * N_ + nn) * HD_ + dd] = __float2half(v * SLOG2E);
                else if (tsel == 1)
                    kh[((size_t)(bb * H_ + hh) * N_ + nn) * HD_ + dd] = __float2half(v);
                else
                    vth[((size_t)(bb * H_ + hh) * HD_ + dd) * VTW + nn] = __float2half(v);
            }
        }
    }
}

// ---------------------------------------------------------------------------
// K2: pos bias (scaled by SCALE*log2e): posh[h][n][m]
// ---------------------------------------------------------------------------
__global__ __launch_bounds__(256) void pos_kernel(
    const float* __restrict__ pe, const float* __restrict__ pw,
    __half* __restrict__ posh)
{
    __shared__ float W[H_][P_];
    const int t = threadIdx.x;
    for (int i = t; i < H_ * P_; i += 256) W[i / P_][i % P_] = pw[i];
    __syncthreads();
    int nm = blockIdx.x * 256 + t;
    if (nm >= N_ * N_) return;
    float e[48];
    const float4* src = (const float4*)(pe + (size_t)nm * 48);
    #pragma unroll
    for (int i = 0; i < 12; ++i) {
        float4 v = src[i];
        e[4*i] = v.x; e[4*i+1] = v.y; e[4*i+2] = v.z; e[4*i+3] = v.w;
    }
    int n = nm / N_, m = nm - n * N_;
    #pragma unroll
    for (int hh = 0; hh < H_; ++hh) {
        float s = 0.f;
        #pragma unroll
        for (int p = 0; p < 48; ++p) s = fmaf(e[p], W[hh][p], s);
        posh[((size_t)hh * N_ + n) * POSW + m] = __float2half(s * SLOG2E);
    }
}

// ---------------------------------------------------------------------------
// K3: MFMA flash attention (r8 structure), bias via DIRECT GLOBAL b64 loads
//     as MFMA C-init (no LDS staging for bias), deferred l-reduction.
// ---------------------------------------------------------------------------
#define NQT 13
#define ATT_NWG (192 * NQT)   // 2496, divisible by 8

__global__ __launch_bounds__(256) void attn_mfma(
    const _Float16* __restrict__ qh, const _Float16* __restrict__ kh,
    const _Float16* __restrict__ vt, const _Float16* __restrict__ posh,
    _Float16* __restrict__ aoh)
{
    __shared__ _Float16 Kl[64][72];          // keys  [m][d]
    __shared__ _Float16 Vl[64][72];          // V^T   [d][m]

    const int t  = threadIdx.x;
    const int w  = t >> 6;                   // wave 0..3
    const int l  = t & 63;
    const int lr = l & 15;
    const int lg = l >> 4;

    const int g2   = xcd_swz(blockIdx.x, ATT_NWG);
    const int qt   = g2 % NQT;
    const int rest = g2 / NQT;
    const int b    = rest & 15;
    const int h    = rest >> 4;
    const int bh   = b * H_ + h;
    const int n0   = qt * 64;

    const int qrow = n0 + w * 16 + lr;
    const int qrc  = qrow < N_ ? qrow : N_ - 1;
    const _Float16* qbase = qh + ((size_t)bh * N_ + qrc) * HD_;
    const half8_t qf0 = *(const half8_t*)(qbase + lg * 8);
    const half8_t qf1 = *(const half8_t*)(qbase + 32 + lg * 8);

    f32x4 O0 = {0.f,0.f,0.f,0.f}, O1 = O0, O2 = O0, O3 = O0;
    float m_run = -1e30f;        // shared per q-row (reduced each chunk)
    float l_lane = 0.f;          // per-lane partial denom (reduced at end)

    const int srow = t >> 2;
    const int scol = (t & 3) * 16;
    const _Float16* kRow = kh + ((size_t)bh * N_) * HD_ + scol;
    const _Float16* vRow = vt + ((size_t)bh * HD_ + srow) * VTW + scol;
    // per-lane bias fragment base: row = this lane's q-row, col base = lg*4
    const _Float16* bFrag = posh + ((size_t)h * N_ + qrc) * POSW + lg * 4;

    half8_t rk0, rk1, rv0, rv1;
    half4_t rbc[4], rbn[4];
    {
        const int gm = srow < N_ ? srow : N_ - 1;
        const half8_t* ks = (const half8_t*)(kRow + (size_t)gm * HD_);
        rk0 = ks[0]; rk1 = ks[1];
        const half8_t* vs = (const half8_t*)vRow;
        rv0 = vs[0]; rv1 = vs[1];
        #pragma unroll
        for (int ms = 0; ms < 4; ++ms)
            rbc[ms] = *(const half4_t*)(bFrag + ms * 16);
    }

    for (int c = 0; c < 13; ++c) {
        *(half8_t*)&Kl[srow][scol]     = rk0;
        *(half8_t*)&Kl[srow][scol + 8] = rk1;
        *(half8_t*)&Vl[srow][scol]     = rv0;
        *(half8_t*)&Vl[srow][scol + 8] = rv1;
        __syncthreads();

        if (c < 12) {
            const int m0n = (c + 1) * 64;
            const int gm  = (m0n + srow) < N_ ? (m0n + srow) : N_ - 1;
            const half8_t* ks = (const half8_t*)(kRow + (size_t)gm * HD_);
            rk0 = ks[0]; rk1 = ks[1];
            const half8_t* vs = (const half8_t*)(vRow + m0n);
            rv0 = vs[0]; rv1 = vs[1];
            #pragma unroll
            for (int ms = 0; ms < 4; ++ms)
                rbn[ms] = *(const half4_t*)(bFrag + m0n + ms * 16);
        }

        // ---- QK^T swapped, bias (global regs) as C-init
        f32x4 s[4];
        __builtin_amdgcn_s_setprio(1);
        #pragma unroll
        for (int ms = 0; ms < 4; ++ms) {
            f32x4 acc = { (float)rbc[ms][0], (float)rbc[ms][1],
                          (float)rbc[ms][2], (float)rbc[ms][3] };
            half8_t k0 = *(const half8_t*)&Kl[ms * 16 + lr][lg * 8];
            half8_t k1 = *(const half8_t*)&Kl[ms * 16 + lr][32 + lg * 8];
            acc = __builtin_amdgcn_mfma_f32_16x16x32_f16(k0, qf0, acc, 0, 0, 0);
            acc = __builtin_amdgcn_mfma_f32_16x16x32_f16(k1, qf1, acc, 0, 0, 0);
            s[ms] = acc;
        }
        __builtin_amdgcn_s_setprio(0);

        // ---- key-validity mask (uniform branch, last chunk only)
        if (c == 12) {
            #pragma unroll
            for (int ms = 0; ms < 4; ++ms)
                #pragma unroll
                for (int r = 0; r < 4; ++r)
                    if (ms * 16 + lg * 4 + r >= 17) s[ms][r] = -1e30f;
        }

        // ---- online softmax (per-lane row; max3-shaped tree)
        float x0 = fmaxf(fmaxf(s[0][0], s[0][1]), s[0][2]);
        float x1 = fmaxf(fmaxf(s[0][3], s[1][0]), s[1][1]);
        float x2 = fmaxf(fmaxf(s[1][2], s[1][3]), s[2][0]);
        float x3 = fmaxf(fmaxf(s[2][1], s[2][2]), s[2][3]);
        float x4 = fmaxf(fmaxf(s[3][0], s[3][1]), s[3][2]);
        float smax = fmaxf(fmaxf(fmaxf(x0, x1), x2),
                           fmaxf(fmaxf(x3, x4), s[3][3]));
        smax = fmaxf(smax, __shfl_xor(smax, 16));
        smax = fmaxf(smax, __shfl_xor(smax, 32));

        if (__any(smax > m_run + 8.f)) {       // defer-max: rescale rarely
            const float mn    = fmaxf(m_run, smax);
            const float alpha = exp2f(m_run - mn);
            m_run = mn;
            l_lane *= alpha;
            const float a0 = __shfl(alpha, lg * 4 + 0);
            const float a1 = __shfl(alpha, lg * 4 + 1);
            const float a2 = __shfl(alpha, lg * 4 + 2);
            const float a3 = __shfl(alpha, lg * 4 + 3);
            O0[0]*=a0; O0[1]*=a1; O0[2]*=a2; O0[3]*=a3;
            O1[0]*=a0; O1[1]*=a1; O1[2]*=a2; O1[3]*=a3;
            O2[0]*=a0; O2[1]*=a1; O2[2]*=a2; O2[3]*=a3;
            O3[0]*=a0; O3[1]*=a1; O3[2]*=a2; O3[3]*=a3;
        }

        float p[4][4];
        float psum = 0.f;
        #pragma unroll
        for (int ms = 0; ms < 4; ++ms)
            #pragma unroll
            for (int r = 0; r < 4; ++r) {
                p[ms][r] = exp2f(s[ms][r] - m_run);
                psum += p[ms][r];
            }
        l_lane += psum;                 // deferred cross-lane reduce

        // ---- pack P into lane-local A-frags (V k-axis permuted to match)
        half8_t pa0 = { (_Float16)p[0][0], (_Float16)p[0][1], (_Float16)p[0][2], (_Float16)p[0][3],
                        (_Float16)p[1][0], (_Float16)p[1][1], (_Float16)p[1][2], (_Float16)p[1][3] };
        half8_t pa1 = { (_Float16)p[2][0], (_Float16)p[2][1], (_Float16)p[2][2], (_Float16)p[2][3],
                        (_Float16)p[3][0], (_Float16)p[3][1], (_Float16)p[3][2], (_Float16)p[3][3] };

        // ---- PV: B-frag = V^T with permuted key columns
        __builtin_amdgcn_s_setprio(1);
        #pragma unroll
        for (int ds = 0; ds < 4; ++ds) {
            const _Float16* vr = &Vl[ds * 16 + lr][0];
            half4_t v00 = *(const half4_t*)&vr[lg * 4];
            half4_t v01 = *(const half4_t*)&vr[16 + lg * 4];
            half4_t v10 = *(const half4_t*)&vr[32 + lg * 4];
            half4_t v11 = *(const half4_t*)&vr[48 + lg * 4];
            half8_t vf0 = __builtin_shufflevector(v00, v01, 0, 1, 2, 3, 4, 5, 6, 7);
            half8_t vf1 = __builtin_shufflevector(v10, v11, 0, 1, 2, 3, 4, 5, 6, 7);
            f32x4& Od = (ds == 0 ? O0 : ds == 1 ? O1 : ds == 2 ? O2 : O3);
            Od = __builtin_amdgcn_mfma_f32_16x16x32_f16(pa0, vf0, Od, 0, 0, 0);
            Od = __builtin_amdgcn_mfma_f32_16x16x32_f16(pa1, vf1, Od, 0, 0, 0);
        }
        __builtin_amdgcn_s_setprio(0);
        __syncthreads();

        #pragma unroll
        for (int ms = 0; ms < 4; ++ms) rbc[ms] = rbn[ms];
    }

    // ---- epilogue: reduce l once; rows n0 + w*16 + lg*4 + r, col d = ds*16+lr
    float l_row = l_lane;
    l_row += __shfl_xor(l_row, 16);
    l_row += __shfl_xor(l_row, 32);
    const int bb = bh / H_;
    #pragma unroll
    for (int r = 0; r < 4; ++r) {
        const int n = n0 + w * 16 + lg * 4 + r;
        if (n >= N_) continue;
        const float lv  = __shfl(l_row, lg * 4 + r);
        const float inv = 1.f / lv;
        _Float16* dst = aoh + ((size_t)(bb * N_ + n)) * C_ + h * HD_;
        dst[0 * 16 + lr] = (_Float16)(O0[r] * inv);
        dst[1 * 16 + lr] = (_Float16)(O1[r] * inv);
        dst[2 * 16 + lr] = (_Float16)(O2[r] * inv);
        dst[3 * 16 + lr] = (_Float16)(O3[r] * inv);
    }
}

// ---------------------------------------------------------------------------
// K4: proj MFMA GEMM, double-buffered + XCD swizzle: out = AO @ Wp^T + bias
// ---------------------------------------------------------------------------
#define PROJ_NWG (6 * 99)

__global__ __launch_bounds__(256) void proj_gemm_mfma(
    const _Float16* __restrict__ A, const _Float16* __restrict__ Bw,
    const float* __restrict__ bias, float* __restrict__ out)
{
    __shared__ _Float16 Asl[2][128 * 32];
    __shared__ _Float16 Bsl[2][128 * 32];

    const int t  = threadIdx.x;
    const int w  = t >> 6;
    const int l  = t & 63;
    const int lr = l & 15;
    const int lg = l >> 4;
    const int wm = (w >> 1) * 64;
    const int wn = (w & 1) * 64;

    const int g  = xcd_swz(blockIdx.x, PROJ_NWG);
    const int n0 = (g % 6) * 128;
    const int m0 = (g / 6) * 128;

    const int f1 = t + 256;
    const int ar0 = t >> 2,  ac0 = (t & 3) * 8;
    const int ar1 = f1 >> 2, ac1 = (f1 & 3) * 8;
    const _Float16* Ag0 = A  + (size_t)(m0 + ar0) * 768 + ac0;
    const _Float16* Ag1 = A  + (size_t)(m0 + ar1) * 768 + ac1;
    const _Float16* Bg0 = Bw + (size_t)(n0 + ar0) * 768 + ac0;
    const _Float16* Bg1 = Bw + (size_t)(n0 + ar1) * 768 + ac1;

    f32x4 acc[4][4];
    #pragma unroll
    for (int i = 0; i < 4; ++i)
        #pragma unroll
        for (int j = 0; j < 4; ++j) acc[i][j] = (f32x4){0.f, 0.f, 0.f, 0.f};

    gl16(Ag0, &Asl[0][t * 8]); gl16(Ag1, &Asl[0][f1 * 8]);
    gl16(Bg0, &Bsl[0][t * 8]); gl16(Bg1, &Bsl[0][f1 * 8]);
    __syncthreads();

    #pragma unroll 2
    for (int it = 0; it < 24; ++it) {
        const int cur = it & 1;
        if (it < 23) {
            const int kn = (it + 1) * 32;
            gl16(Ag0 + kn, &Asl[cur ^ 1][t * 8]); gl16(Ag1 + kn, &Asl[cur ^ 1][f1 * 8]);
            gl16(Bg0 + kn, &Bsl[cur ^ 1][t * 8]); gl16(Bg1 + kn, &Bsl[cur ^ 1][f1 * 8]);
        }
        half8_t af[4], bf[4];
        #pragma unroll
        for (int i = 0; i < 4; ++i)
            af[i] = *(const half8_t*)&Asl[cur][(wm + i * 16 + lr) * 32 + lg * 8];
        #pragma unroll
        for (int j = 0; j < 4; ++j)
            bf[j] = *(const half8_t*)&Bsl[cur][(wn + j * 16 + lr) * 32 + lg * 8];
        __builtin_amdgcn_s_setprio(1);
        #pragma unroll
        for (int i = 0; i < 4; ++i)
            #pragma unroll
            for (int j = 0; j < 4; ++j)
                acc[i][j] = __builtin_amdgcn_mfma_f32_16x16x32_f16(af[i], bf[j], acc[i][j], 0, 0, 0);
        __builtin_amdgcn_s_setprio(0);
        __syncthreads();
    }

    float bj[4];
    #pragma unroll
    for (int j = 0; j < 4; ++j) bj[j] = bias[n0 + wn + j * 16 + lr];
    #pragma unroll
    for (int i = 0; i < 4; ++i) {
        #pragma unroll
        for (int r = 0; r < 4; ++r) {
            const int m = m0 + wm + i * 16 + lg * 4 + r;
            if (m >= M_) continue;
            #pragma unroll
            for (int j = 0; j < 4; ++j) {
                const int n = n0 + wn + j * 16 + lr;
                out[(size_t)m * 768 + n] = acc[i][j][r] + bj[j];
            }
        }
    }
}

// ---------------------------------------------------------------------------
extern "C" void kernel_launch(void* const* d_in, const int* in_sizes, int n_in,
                              void* d_out, int out_size, void* d_ws, size_t ws_size,
                              hipStream_t stream)
{
    const float* x     = (const float*)d_in[0];
    const float* qkv_w = (const float*)d_in[1];
    const float* pe    = (const float*)d_in[2];
    const float* pw    = (const float*)d_in[3];
    const float* pjw   = (const float*)d_in[4];
    const float* pjb   = (const float*)d_in[5];
    float* out = (float*)d_out;

    _Float16* wsh  = (_Float16*)d_ws;
    _Float16* qh   = wsh + OFF_Q;
    _Float16* kh   = wsh + OFF_K;
    _Float16* vth  = wsh + OFF_VT;
    _Float16* posh = wsh + OFF_POS;
    _Float16* xf   = wsh + OFF_XF;
    _Float16* aoh  = wsh + OFF_AO;       // aliases xf (x dead after qkv_gemm)
    _Float16* wqf  = wsh + OFF_WQ;
    _Float16* wpf  = wsh + OFF_WP;

    convert_f16<<<dim3(NTOT4 / 256), 256, 0, stream>>>(x, qkv_w, pjw, xf, wqf, wpf);
    qkv_gemm_mfma<<<dim3(QKV_NWG), 256, 0, stream>>>(
        xf, wqf, (__half*)qh, (__half*)kh, (__half*)vth);
    pos_kernel<<<dim3((N_ * N_ + 255) / 256), 256, 0, stream>>>(pe, pw, (__half*)posh);
    attn_mfma<<<dim3(ATT_NWG), 256, 0, stream>>>(qh, kh, vth, posh, aoh);
    proj_gemm_mfma<<<dim3(PROJ_NWG), 256, 0, stream>>>(aoh, wpf, pjb, out);
}